// Round 1
// baseline (23.760 us; speedup 1.0000x reference)
//
#include <hip/hip_runtime.h>
#include <math.h>

#define B   16
#define C   8
#define LC  30
#define VC  10000
#define LP  64
#define VP  2000
#define N_IV 128
#define BETA 0.7f

constexpr int CAP_ROWS  = B * C * LC;   // 3840
constexpr int PROG_ROWS = B * LP;       // 1024

// One block per logit row. Inactive rows write 0 and exit (saves ~2/3 of HBM
// traffic vs streaming the full tensor). Active rows: online logsumexp.
__global__ __launch_bounds__(256) void rows_kernel(
    const float* __restrict__ pred_cap,  const int* __restrict__ gt_cap,
    const int*  __restrict__ cap_lens,   const int* __restrict__ caps_count,
    const float* __restrict__ pred_prog, const int* __restrict__ gt_prog,
    const int*  __restrict__ prog_len,
    float* __restrict__ cap_part, float* __restrict__ prog_part)
{
    const int bid = blockIdx.x;
    const int tid = threadIdx.x;

    const float* row;
    float*       outp;
    int          tgt, V;
    float        w;

    if (bid < CAP_ROWS) {
        const int b   = bid / (C * LC);
        const int rem = bid % (C * LC);
        const int c   = rem / LC;
        const int t   = rem % LC;
        const int cnt = caps_count[b];
        const int len = cap_lens[b * C + c];
        if (c >= cnt || t >= len) {
            if (tid == 0) cap_part[bid] = 0.0f;
            return;
        }
        row  = pred_cap + (size_t)bid * VC;
        tgt  = gt_cap[bid];
        w    = powf((float)len, -BETA);
        outp = cap_part + bid;
        V    = VC;
    } else {
        const int pbid = bid - CAP_ROWS;
        const int b    = pbid / LP;
        const int t    = pbid % LP;
        const int len  = prog_len[b];
        if (t >= len) {
            if (tid == 0) prog_part[pbid] = 0.0f;
            return;
        }
        row  = pred_prog + (size_t)pbid * VP;
        tgt  = gt_prog[pbid];
        w    = powf((float)len, -BETA);
        outp = prog_part + pbid;
        V    = VP;
    }

    // ---- one-pass online logsumexp over V elements (V % 4 == 0) ----
    float m = -INFINITY, s = 0.0f;
    const float4* row4 = (const float4*)row;
    const int n4 = V >> 2;
    for (int j = tid; j < n4; j += 256) {
        float4 v = row4[j];
        float mx = fmaxf(fmaxf(v.x, v.y), fmaxf(v.z, v.w));
        float mn = fmaxf(m, mx);
        s = s * __expf(m - mn)
          + __expf(v.x - mn) + __expf(v.y - mn)
          + __expf(v.z - mn) + __expf(v.w - mn);
        m = mn;
    }

    // wave(64) reduction of the (m, s) pair
    #pragma unroll
    for (int off = 1; off < 64; off <<= 1) {
        float m2 = __shfl_xor(m, off, 64);
        float s2 = __shfl_xor(s, off, 64);
        float mn = fmaxf(m, m2);
        s = s * __expf(m - mn) + s2 * __expf(m2 - mn);
        m = mn;
    }

    __shared__ float sm[4], ss[4];
    const int wid = tid >> 6;
    if ((tid & 63) == 0) { sm[wid] = m; ss[wid] = s; }
    __syncthreads();

    if (tid == 0) {
        float M = sm[0], S = ss[0];
        #pragma unroll
        for (int i = 1; i < 4; i++) {
            float mn = fmaxf(M, sm[i]);
            S = S * __expf(M - mn) + ss[i] * __expf(sm[i] - mn);
            M = mn;
        }
        const float lse    = M + logf(S);
        const float logp_t = row[tgt] - lse;
        *outp = -w * logp_t;
    }
}

__device__ inline float wave_sum(float v) {
    #pragma unroll
    for (int off = 32; off; off >>= 1) v += __shfl_xor(v, off, 64);
    return v;
}

// Single block: deterministic reduction of partials + IoU + final combine.
__global__ __launch_bounds__(256) void finish_kernel(
    const float* __restrict__ cap_part, const float* __restrict__ prog_part,
    const int*  __restrict__ caps_count,
    const float* __restrict__ pred_iv, const float* __restrict__ gt_iv,
    const float* __restrict__ scores, float* __restrict__ out)
{
    const int tid = threadIdx.x;

    float cs = 0.0f;
    for (int i = tid; i < CAP_ROWS; i += 256) cs += cap_part[i];
    float ps = 0.0f;
    for (int i = tid; i < PROG_ROWS; i += 256) ps += prog_part[i];

    float is = 0.0f;
    if (tid < N_IV) {
        const float p0 = pred_iv[tid * 2 + 0];
        const float p1 = pred_iv[tid * 2 + 1];
        const float g0 = gt_iv[tid * 2 + 0];
        const float g1 = gt_iv[tid * 2 + 1];
        const float inter = fmaxf(fminf(p1, g1) - fmaxf(p0, g0), 0.0f);
        const float uni   = fmaxf(p1, g1) - fminf(p0, g0);
        is = inter / uni;
    }

    float nc = 0.0f;
    if (tid < B) nc = (float)caps_count[tid];

    cs = wave_sum(cs);
    ps = wave_sum(ps);
    is = wave_sum(is);
    nc = wave_sum(nc);

    __shared__ float red[4][4];
    const int wid = tid >> 6;
    if ((tid & 63) == 0) {
        red[0][wid] = cs; red[1][wid] = ps; red[2][wid] = is; red[3][wid] = nc;
    }
    __syncthreads();

    if (tid == 0) {
        float CS = red[0][0] + red[0][1] + red[0][2] + red[0][3];
        float PS = red[1][0] + red[1][1] + red[1][2] + red[1][3];
        float IS = red[2][0] + red[2][1] + red[2][2] + red[2][3];
        float NC = red[3][0] + red[3][1] + red[3][2] + red[3][3];

        const float cap_loss  = CS / NC;
        const float prog_loss = PS / (float)B;
        const float iou_loss  = 1.0f - IS / (float)N_IV;
        const float loss = scores[0] * cap_loss + scores[1] * prog_loss
                         + scores[2] * iou_loss;
        out[0] = loss;
        out[1] = cap_loss;
        out[2] = prog_loss;
        out[3] = iou_loss;
    }
}

extern "C" void kernel_launch(void* const* d_in, const int* in_sizes, int n_in,
                              void* d_out, int out_size, void* d_ws, size_t ws_size,
                              hipStream_t stream) {
    const int*   gt_captions    = (const int*)  d_in[0];
    const int*   gt_cap_lens    = (const int*)  d_in[1];
    const float* pred_captions  = (const float*)d_in[2];
    const int*   gt_program     = (const int*)  d_in[3];
    const int*   gt_prog_len    = (const int*)  d_in[4];
    const float* pred_program   = (const float*)d_in[5];
    const float* gt_intervals   = (const float*)d_in[6];
    const float* pred_intervals = (const float*)d_in[7];
    const int*   gt_caps_count  = (const int*)  d_in[8];
    const float* scores         = (const float*)d_in[9];
    float* out = (float*)d_out;

    float* cap_part  = (float*)d_ws;
    float* prog_part = cap_part + CAP_ROWS;

    rows_kernel<<<CAP_ROWS + PROG_ROWS, 256, 0, stream>>>(
        pred_captions, gt_captions, gt_cap_lens, gt_caps_count,
        pred_program, gt_program, gt_prog_len,
        cap_part, prog_part);

    finish_kernel<<<1, 256, 0, stream>>>(
        cap_part, prog_part, gt_caps_count,
        pred_intervals, gt_intervals, scores, out);
}

// Round 2
// 22.770 us; speedup vs baseline: 1.0435x; 1.0435x over previous
//
#include <hip/hip_runtime.h>
#include <math.h>

#define B   16
#define C   8
#define LC  30
#define VC  10000
#define LP  64
#define VP  2000
#define N_IV 128
#define BETA 0.7f

constexpr int CAP_ROWS    = B * C * LC;    // 3840
constexpr int PROG_ROWS   = B * LP;        // 1024
constexpr int PROG_BLOCKS = PROG_ROWS / 4; // 256 (4 waves/block, 1 row/wave)
constexpr int N4C = VC / 4;                // 2500 float4 per cap row
constexpr int KC  = (N4C + 255) / 256;     // 10 per thread
constexpr int N4P = VP / 4;                // 500 float4 per prog row
constexpr int KP  = (N4P + 63) / 64;       // 8 per lane

// One 256-thread block per caption row; one wave per program row.
// Batch-load the full row into registers (max MLP), then max-reduce,
// then exp-sum from registers: single memory pass, single waitcnt.
__global__ __launch_bounds__(256) void rows_kernel(
    const float* __restrict__ pred_cap,  const int* __restrict__ gt_cap,
    const int*  __restrict__ cap_lens,   const int* __restrict__ caps_count,
    const float* __restrict__ pred_prog, const int* __restrict__ gt_prog,
    const int*  __restrict__ prog_len,
    float* __restrict__ cap_part, float* __restrict__ prog_part)
{
    __shared__ float sred[4];
    __shared__ float ssum[4];

    const int bid = blockIdx.x;
    const int tid = threadIdx.x;

    if (bid < CAP_ROWS) {
        // ---------------- caption row: V = 10000 ----------------
        const int b   = bid / (C * LC);
        const int rem = bid % (C * LC);
        const int c   = rem / LC;
        const int t   = rem % LC;
        const int len = cap_lens[b * C + c];
        if (c >= caps_count[b] || t >= len) {
            if (tid == 0) cap_part[bid] = 0.0f;
            return;
        }
        const float*  row  = pred_cap + (size_t)bid * VC;
        const float4* row4 = (const float4*)row;

        float4 v[KC];
        #pragma unroll
        for (int k = 0; k < KC; k++) {
            const int j = tid + k * 256;
            if (j < N4C) v[k] = row4[j];
            else v[k] = make_float4(-INFINITY, -INFINITY, -INFINITY, -INFINITY);
        }

        float m = -INFINITY;
        #pragma unroll
        for (int k = 0; k < KC; k++)
            m = fmaxf(m, fmaxf(fmaxf(v[k].x, v[k].y), fmaxf(v[k].z, v[k].w)));
        #pragma unroll
        for (int off = 32; off; off >>= 1) m = fmaxf(m, __shfl_xor(m, off, 64));

        const int wid = tid >> 6;
        if ((tid & 63) == 0) sred[wid] = m;
        __syncthreads();
        const float M = fmaxf(fmaxf(sred[0], sred[1]), fmaxf(sred[2], sred[3]));

        float s = 0.0f;
        #pragma unroll
        for (int k = 0; k < KC; k++)
            s += __expf(v[k].x - M) + __expf(v[k].y - M)
               + __expf(v[k].z - M) + __expf(v[k].w - M);
        #pragma unroll
        for (int off = 32; off; off >>= 1) s += __shfl_xor(s, off, 64);

        if ((tid & 63) == 0) ssum[wid] = s;
        __syncthreads();

        if (tid == 0) {
            const float S   = ssum[0] + ssum[1] + ssum[2] + ssum[3];
            const float lse = M + logf(S);
            const float w   = powf((float)len, -BETA);
            cap_part[bid] = -w * (row[gt_cap[bid]] - lse);
        }
    } else {
        // ---------------- program rows: V = 2000, 1 wave per row ----------------
        const int pb   = bid - CAP_ROWS;
        const int lane = tid & 63;
        const int wid  = tid >> 6;
        const int r    = pb * 4 + wid;          // < PROG_ROWS by grid sizing
        const int b    = r / LP;
        const int t    = r % LP;
        const int len  = prog_len[b];
        if (t >= len) {
            if (lane == 0) prog_part[r] = 0.0f;
            return;
        }
        const float*  row  = pred_prog + (size_t)r * VP;
        const float4* row4 = (const float4*)row;

        float4 v[KP];
        #pragma unroll
        for (int k = 0; k < KP; k++) {
            const int j = lane + k * 64;
            if (j < N4P) v[k] = row4[j];
            else v[k] = make_float4(-INFINITY, -INFINITY, -INFINITY, -INFINITY);
        }

        float m = -INFINITY;
        #pragma unroll
        for (int k = 0; k < KP; k++)
            m = fmaxf(m, fmaxf(fmaxf(v[k].x, v[k].y), fmaxf(v[k].z, v[k].w)));
        #pragma unroll
        for (int off = 32; off; off >>= 1) m = fmaxf(m, __shfl_xor(m, off, 64));

        float s = 0.0f;
        #pragma unroll
        for (int k = 0; k < KP; k++)
            s += __expf(v[k].x - m) + __expf(v[k].y - m)
               + __expf(v[k].z - m) + __expf(v[k].w - m);
        #pragma unroll
        for (int off = 32; off; off >>= 1) s += __shfl_xor(s, off, 64);

        if (lane == 0) {
            const float lse = m + logf(s);
            const float w   = powf((float)len, -BETA);
            prog_part[r] = -w * (row[gt_prog[r]] - lse);
        }
    }
}

__device__ inline float wave_sum(float v) {
    #pragma unroll
    for (int off = 32; off; off >>= 1) v += __shfl_xor(v, off, 64);
    return v;
}

// Single block: deterministic reduction of partials + IoU + final combine.
__global__ __launch_bounds__(256) void finish_kernel(
    const float* __restrict__ cap_part, const float* __restrict__ prog_part,
    const int*  __restrict__ caps_count,
    const float* __restrict__ pred_iv, const float* __restrict__ gt_iv,
    const float* __restrict__ scores, float* __restrict__ out)
{
    const int tid = threadIdx.x;

    float cs = 0.0f;
    for (int i = tid; i < CAP_ROWS; i += 256) cs += cap_part[i];
    float ps = 0.0f;
    for (int i = tid; i < PROG_ROWS; i += 256) ps += prog_part[i];

    float is = 0.0f;
    if (tid < N_IV) {
        const float p0 = pred_iv[tid * 2 + 0];
        const float p1 = pred_iv[tid * 2 + 1];
        const float g0 = gt_iv[tid * 2 + 0];
        const float g1 = gt_iv[tid * 2 + 1];
        const float inter = fmaxf(fminf(p1, g1) - fmaxf(p0, g0), 0.0f);
        const float uni   = fmaxf(p1, g1) - fminf(p0, g0);
        is = inter / uni;
    }

    float nc = 0.0f;
    if (tid < B) nc = (float)caps_count[tid];

    cs = wave_sum(cs);
    ps = wave_sum(ps);
    is = wave_sum(is);
    nc = wave_sum(nc);

    __shared__ float red[4][4];
    const int wid = tid >> 6;
    if ((tid & 63) == 0) {
        red[0][wid] = cs; red[1][wid] = ps; red[2][wid] = is; red[3][wid] = nc;
    }
    __syncthreads();

    if (tid == 0) {
        const float CS = red[0][0] + red[0][1] + red[0][2] + red[0][3];
        const float PS = red[1][0] + red[1][1] + red[1][2] + red[1][3];
        const float IS = red[2][0] + red[2][1] + red[2][2] + red[2][3];
        const float NC = red[3][0] + red[3][1] + red[3][2] + red[3][3];

        const float cap_loss  = CS / NC;
        const float prog_loss = PS / (float)B;
        const float iou_loss  = 1.0f - IS / (float)N_IV;
        const float loss = scores[0] * cap_loss + scores[1] * prog_loss
                         + scores[2] * iou_loss;
        out[0] = loss;
        out[1] = cap_loss;
        out[2] = prog_loss;
        out[3] = iou_loss;
    }
}

extern "C" void kernel_launch(void* const* d_in, const int* in_sizes, int n_in,
                              void* d_out, int out_size, void* d_ws, size_t ws_size,
                              hipStream_t stream) {
    const int*   gt_captions    = (const int*)  d_in[0];
    const int*   gt_cap_lens    = (const int*)  d_in[1];
    const float* pred_captions  = (const float*)d_in[2];
    const int*   gt_program     = (const int*)  d_in[3];
    const int*   gt_prog_len    = (const int*)  d_in[4];
    const float* pred_program   = (const float*)d_in[5];
    const float* gt_intervals   = (const float*)d_in[6];
    const float* pred_intervals = (const float*)d_in[7];
    const int*   gt_caps_count  = (const int*)  d_in[8];
    const float* scores         = (const float*)d_in[9];
    float* out = (float*)d_out;

    float* cap_part  = (float*)d_ws;
    float* prog_part = cap_part + CAP_ROWS;

    rows_kernel<<<CAP_ROWS + PROG_BLOCKS, 256, 0, stream>>>(
        pred_captions, gt_captions, gt_cap_lens, gt_caps_count,
        pred_program, gt_program, gt_prog_len,
        cap_part, prog_part);

    finish_kernel<<<1, 256, 0, stream>>>(
        cap_part, prog_part, gt_caps_count,
        pred_intervals, gt_intervals, scores, out);
}